// Round 7
// baseline (257.550 us; speedup 1.0000x reference)
//
#include <hip/hip_runtime.h>
#include <hip/hip_bf16.h>

typedef short short8 __attribute__((ext_vector_type(8)));
typedef float f32x4 __attribute__((ext_vector_type(4)));

#define M_TOT 16384   // B*S = 4*4096
#define NDIM  1024    // D = U = 1024
#define BK 32
#define NT (NDIM / BK)   // 32 K-tiles

static __device__ __forceinline__ unsigned short f2bf(float f) {
  unsigned int u = __builtin_bit_cast(unsigned int, f);
  unsigned int r = (u + 0x7fffu + ((u >> 16) & 1u)) >> 16;   // RN-even
  return (unsigned short)r;
}
static __device__ __forceinline__ float bf2f(unsigned short u) {
  return __builtin_bit_cast(float, ((unsigned int)u) << 16);
}

// compile-time-only reorder fence (zero runtime cost)
#define CLB() asm volatile("" ::: "memory")
#define VMW(N) asm volatile("s_waitcnt vmcnt(" #N ")" ::: "memory")
#define BAR() do { CLB(); __builtin_amdgcn_s_barrier(); CLB(); } while (0)

// ---------------- cast inputs fp32 -> bf16, vectorized ----------------
__global__ __launch_bounds__(256) void cast_in(const float* __restrict__ in,
                                               unsigned short* __restrict__ out,
                                               int n4) {
  int i = blockIdx.x * 256 + threadIdx.x;
  if (i >= n4) return;
  float4 v = reinterpret_cast<const float4*>(in)[i];
  ushort4 o;
  o.x = f2bf(v.x); o.y = f2bf(v.y); o.z = f2bf(v.z); o.w = f2bf(v.w);
  reinterpret_cast<ushort4*>(out)[i] = o;
}

// ---- transpose-cast 4 weights fp32 [K][N] -> bf16 [N][K], one launch ----
__global__ __launch_bounds__(256) void tcast4(
    const float* __restrict__ w1, const float* __restrict__ w2,
    const float* __restrict__ wg, const float* __restrict__ ws,
    unsigned short* __restrict__ W1t, unsigned short* __restrict__ W2t,
    unsigned short* __restrict__ Wgt, unsigned short* __restrict__ Wst) {
  const int z = blockIdx.z;
  const float* src = (z == 0) ? w1 : (z == 1) ? w2 : (z == 2) ? wg : ws;
  unsigned short* dst = (z == 0) ? W1t : (z == 1) ? W2t : (z == 2) ? Wgt : Wst;
  __shared__ unsigned short tile[32][33];
  int bx = blockIdx.x * 32, by = blockIdx.y * 32;
  int x = threadIdx.x & 31, y = threadIdx.x >> 5;  // 32 x 8
#pragma unroll
  for (int i = 0; i < 32; i += 8)
    tile[y + i][x] = f2bf(src[(size_t)(by + y + i) * NDIM + bx + x]);
  __syncthreads();
#pragma unroll
  for (int i = 0; i < 32; i += 8)
    dst[(size_t)(bx + y + i) * NDIM + by + x] = tile[x][y + i];
}

// ========== tri-GEMM: stage A once, multiply against 3 weights ==========
// H = bf16(relu(x@W1+b1)); G = bf16(sigmoid(x@Wg+bg)); S = bf16(x@Ws+bs)
// (unchanged from round 6: 128x128/weight, 4 waves, BK=32, 2 blocks/CU)
__global__ __launch_bounds__(256, 2) void trigemm(
    const unsigned short* __restrict__ A,
    const unsigned short* __restrict__ W1t,
    const unsigned short* __restrict__ Wgt,
    const unsigned short* __restrict__ Wst,
    const float* __restrict__ b1,
    const float* __restrict__ bg,
    const float* __restrict__ bs,
    unsigned short* __restrict__ H,
    unsigned short* __restrict__ G,
    unsigned short* __restrict__ S) {
  __shared__ __align__(16) unsigned short lds[2][4][128][BK];  // 64 KB

  const int tid = threadIdx.x;
  const int lane = tid & 63;
  const int wave = tid >> 6;            // 0..3
  const int wm = wave >> 1;             // 0..1
  const int wn = wave & 1;              // 0..1

  const int id = blockIdx.x;
  const int xcd = id & 7;
  const int slot = id >> 3;                // 0..127
  const int rblk = xcd + 8 * (slot >> 3);  // 0..127
  const int cblk = slot & 7;               // 0..7
  const int m0 = rblk * 128, n0 = cblk * 128;

  const unsigned short* gA = A + (size_t)m0 * NDIM;
  const unsigned short* gW[3] = {W1t + (size_t)n0 * NDIM, Wgt + (size_t)n0 * NDIM,
                                 Wst + (size_t)n0 * NDIM};

  f32x4 acc[3][4][4] = {};

  auto stage = [&](int buf, int kt) {
#pragma unroll
    for (int q = 0; q < 8; ++q) {
      const int mat = q >> 1;              // compile-time: 0=A,1..3=W
      int local = (q & 1) * 256 + tid;     // chunk within mat, 0..511
      int row = local >> 2;                // 0..127
      int c = (local & 3) ^ ((row >> 1) & 3);  // pre-swizzled global k-chunk
      const unsigned short* g =
          (mat == 0 ? gA : gW[mat - 1]) + (size_t)row * NDIM + kt * BK + c * 8;
      unsigned short* l = &lds[buf][0][0][0] +
                          (size_t)(q * 256 + (tid & ~63)) * 8;  // wave-uniform base
      __builtin_amdgcn_global_load_lds(
          (__attribute__((address_space(1))) void*)g,
          (__attribute__((address_space(3))) void*)l, 16, 0, 0);
    }
  };

  auto compute = [&](int buf) {
    short8 af[4];
#pragma unroll
    for (int mi = 0; mi < 4; ++mi) {
      int row = wm * 64 + mi * 16 + (lane & 15);
      int cs = (lane >> 4) ^ ((row >> 1) & 3);
      af[mi] = *reinterpret_cast<const short8*>(&lds[buf][0][row][cs * 8]);
    }
#pragma unroll
    for (int w = 0; w < 3; ++w) {
      short8 bf[4];
#pragma unroll
      for (int nj = 0; nj < 4; ++nj) {
        int row = wn * 64 + nj * 16 + (lane & 15);
        int cs = (lane >> 4) ^ ((row >> 1) & 3);
        bf[nj] = *reinterpret_cast<const short8*>(&lds[buf][1 + w][row][cs * 8]);
      }
      __builtin_amdgcn_s_setprio(1);
#pragma unroll
      for (int mi = 0; mi < 4; ++mi)
#pragma unroll
        for (int nj = 0; nj < 4; ++nj)
          acc[w][mi][nj] = __builtin_amdgcn_mfma_f32_16x16x32_bf16(
              af[mi], bf[nj], acc[w][mi][nj], 0, 0, 0);
      __builtin_amdgcn_s_setprio(0);
    }
  };

  stage(0, 0);
  for (int t = 0; t < NT; ++t) {
    const int cur = t & 1;
    if (t + 1 < NT) {
      stage(cur ^ 1, t + 1);
      VMW(8);
    } else {
      VMW(0);
    }
    BAR();
    compute(cur);
    BAR();
  }

  const int crow0 = m0 + wm * 64;
  const int ccol0 = n0 + wn * 64;
#pragma unroll
  for (int w = 0; w < 3; ++w) {
    const float* bptr = (w == 0) ? b1 : (w == 1) ? bg : bs;
    unsigned short* optr = (w == 0) ? H : (w == 1) ? G : S;
#pragma unroll
    for (int mi = 0; mi < 4; ++mi) {
#pragma unroll
      for (int nj = 0; nj < 4; ++nj) {
        int row = crow0 + mi * 16 + ((lane >> 4) << 2);
        int col = ccol0 + nj * 16 + (lane & 15);
        float bc = bptr[col];
#pragma unroll
        for (int r = 0; r < 4; ++r) {
          float v = acc[w][mi][nj][r] + bc;
          if (w == 0) v = fmaxf(v, 0.f);
          else if (w == 1) v = 1.f / (1.f + __expf(-v));
          optr[(size_t)(row + r) * NDIM + col] = f2bf(v);
        }
      }
    }
  }
}

// ====== fused GEMM-2 + gate + skip + LayerNorm, LDS-free fragments ======
// Out[m] = LN( (H@W2^T + b2) * G + S ) * gamma + beta   (fp32 out)
// Block = 64 rows x 1024 cols (full rows), 8 waves x 128 cols each.
// No LDS staging: waves don't share any W2/H byte within their col slice;
// cross-block W2 reuse is served by L2 (2 MB, XCD-resident), H k-slices
// by L1. Fragments are loaded global->VGPR, one-tile register double
// buffer, compiler-managed waits.
__global__ __launch_bounds__(512, 2) void gemm_y_ln(
    const unsigned short* __restrict__ H,
    const unsigned short* __restrict__ W2t,
    const float* __restrict__ b2,
    const unsigned short* __restrict__ G,
    const unsigned short* __restrict__ S,
    const float* __restrict__ gamma,
    const float* __restrict__ beta,
    float* __restrict__ Out) {
  const int tid = threadIdx.x;
  const int lane = tid & 63;
  const int wave = tid >> 6;        // 0..7 -> 128-col slice
  const int m0 = blockIdx.x * 64;
  const int c0 = wave * 128;
  const int lr = lane & 15;         // row (A) / col (B) within fragment
  const int lk = lane >> 4;         // k-chunk 0..3 (8 bf16 each)

  const unsigned short* aBase = H + (size_t)(m0 + lr) * NDIM + lk * 8;
  const unsigned short* bBase = W2t + (size_t)(c0 + lr) * NDIM + lk * 8;

  f32x4 acc[4][8] = {};
  short8 aA[4], bA[8], aB[4], bB[8];

  auto loadA = [&](short8* d, int kt) {
#pragma unroll
    for (int mi = 0; mi < 4; ++mi)
      d[mi] = *reinterpret_cast<const short8*>(aBase + (size_t)mi * 16 * NDIM + kt * BK);
  };
  auto loadB = [&](short8* d, int kt) {
#pragma unroll
    for (int nj = 0; nj < 8; ++nj)
      d[nj] = *reinterpret_cast<const short8*>(bBase + (size_t)nj * 16 * NDIM + kt * BK);
  };
  auto mfmaAll = [&](short8* a, short8* b) {
#pragma unroll
    for (int mi = 0; mi < 4; ++mi)
#pragma unroll
      for (int nj = 0; nj < 8; ++nj)
        acc[mi][nj] = __builtin_amdgcn_mfma_f32_16x16x32_bf16(
            a[mi], b[nj], acc[mi][nj], 0, 0, 0);
  };

  loadA(aA, 0); loadB(bA, 0);
  for (int t = 0; t < NT; t += 2) {
    loadA(aB, t + 1); loadB(bB, t + 1);         // t+1 <= 31 always
    mfmaAll(aA, bA);
    if (t + 2 < NT) { loadA(aA, t + 2); loadB(bA, t + 2); }
    mfmaAll(aB, bB);
  }

  // ---- epilogue: bias, gate, skip (fp32), per-row sums ----
  float bcol[8], gmc[8], btc[8];
#pragma unroll
  for (int nj = 0; nj < 8; ++nj) {
    int col = c0 + nj * 16 + lr;
    bcol[nj] = b2[col];
    gmc[nj] = gamma[col];
    btc[nj] = beta[col];
  }

  float s1[4][4], s2[4][4];
#pragma unroll
  for (int mi = 0; mi < 4; ++mi) {
#pragma unroll
    for (int r = 0; r < 4; ++r) {
      int row = m0 + mi * 16 + lk * 4 + r;
      float rs1 = 0.f, rs2 = 0.f;
#pragma unroll
      for (int nj = 0; nj < 8; ++nj) {
        int col = c0 + nj * 16 + lr;
        size_t idx = (size_t)row * NDIM + col;
        float v = acc[mi][nj][r] + bcol[nj];
        v = v * bf2f(G[idx]) + bf2f(S[idx]);
        acc[mi][nj][r] = v;
        rs1 += v; rs2 += v * v;
      }
      s1[mi][r] = rs1; s2[mi][r] = rs2;
    }
  }

  // reduce across the 16 lanes sharing the same row set (cols)
#pragma unroll
  for (int off = 1; off < 16; off <<= 1) {
#pragma unroll
    for (int mi = 0; mi < 4; ++mi)
#pragma unroll
      for (int r = 0; r < 4; ++r) {
        s1[mi][r] += __shfl_xor(s1[mi][r], off, 16);
        s2[mi][r] += __shfl_xor(s2[mi][r], off, 16);
      }
  }

  // cross-wave reduce via tiny LDS
  __shared__ float redS[8][64];
  __shared__ float redQ[8][64];
  __shared__ float2 fin[64];
#pragma unroll
  for (int kk = 0; kk < 16; ++kk) {
    if ((lane & 15) == kk) {
      int rl = (kk >> 2) * 16 + lk * 4 + (kk & 3);
      redS[wave][rl] = s1[kk >> 2][kk & 3];
      redQ[wave][rl] = s2[kk >> 2][kk & 3];
    }
  }
  __syncthreads();
  if (tid < 64) {
    float a1 = 0.f, a2 = 0.f;
#pragma unroll
    for (int w = 0; w < 8; ++w) { a1 += redS[w][tid]; a2 += redQ[w][tid]; }
    float mu = a1 * (1.f / NDIM);
    float var = a2 * (1.f / NDIM) - mu * mu;
    fin[tid] = make_float2(mu, rsqrtf(var + 1e-3f));
  }
  __syncthreads();

  // normalize + write fp32
#pragma unroll
  for (int mi = 0; mi < 4; ++mi) {
#pragma unroll
    for (int r = 0; r < 4; ++r) {
      int rl = mi * 16 + lk * 4 + r;
      float2 f = fin[rl];
      float* orow = Out + (size_t)(m0 + rl) * NDIM;
#pragma unroll
      for (int nj = 0; nj < 8; ++nj) {
        int col = c0 + nj * 16 + lr;
        orow[col] = (acc[mi][nj][r] - f.x) * f.y * gmc[nj] + btc[nj];
      }
    }
  }
}

extern "C" void kernel_launch(void* const* d_in, const int* in_sizes, int n_in,
                              void* d_out, int out_size, void* d_ws, size_t ws_size,
                              hipStream_t stream) {
  const float* inp = (const float*)d_in[0];
  const float* w1 = (const float*)d_in[1];
  const float* b1 = (const float*)d_in[2];
  const float* w2 = (const float*)d_in[3];
  const float* b2 = (const float*)d_in[4];
  const float* wg = (const float*)d_in[5];
  const float* bg = (const float*)d_in[6];
  const float* wsk = (const float*)d_in[7];
  const float* bs = (const float*)d_in[8];
  const float* gamma = (const float*)d_in[9];
  const float* beta = (const float*)d_in[10];

  char* p = (char*)d_ws;
  const size_t act_bf16 = (size_t)M_TOT * NDIM * 2;
  const size_t w_bf16 = (size_t)NDIM * NDIM * 2;
  unsigned short* Ain = (unsigned short*)p; p += act_bf16;
  unsigned short* H   = (unsigned short*)p; p += act_bf16;
  unsigned short* G   = (unsigned short*)p; p += act_bf16;
  unsigned short* S   = (unsigned short*)p; p += act_bf16;
  unsigned short* W1t = (unsigned short*)p; p += w_bf16;
  unsigned short* W2t = (unsigned short*)p; p += w_bf16;
  unsigned short* Wgt = (unsigned short*)p; p += w_bf16;
  unsigned short* Wst = (unsigned short*)p; p += w_bf16;

  cast_in<<<(M_TOT * NDIM / 4 + 255) / 256, 256, 0, stream>>>(inp, Ain, M_TOT * NDIM / 4);
  tcast4<<<dim3(32, 32, 4), 256, 0, stream>>>(w1, w2, wg, wsk, W1t, W2t, Wgt, Wst);

  trigemm<<<(M_TOT / 128) * (NDIM / 128), 256, 0, stream>>>(
      Ain, W1t, Wgt, Wst, b1, bg, bs, H, G, S);
  gemm_y_ln<<<M_TOT / 64, 512, 0, stream>>>(H, W2t, b2, G, S, gamma, beta,
                                            (float*)d_out);
}